// Round 1
// baseline (146.199 us; speedup 1.0000x reference)
//
#include <hip/hip_runtime.h>

// Problem shape (fixed by setup_inputs): b=2, T=8192, h=16, p=64, n=64, l=64
#define B_SZ 2
#define T_SZ 8192
#define H_SZ 16
#define P_SZ 64
#define N_SZ 64
#define L_SZ 64
#define C_SZ (T_SZ / L_SZ)   // 128 chunks
// Skip threshold on the after-chunk suffix sum. exp(-30) ~ 9e-14; worst-case
// skipped contribution per element ~ 64 * e^-30 * maxX*maxB * 128 chunks ~ 1e-8,
// vs validation threshold ~0.3. Very conservative.
#define SKIP_THRESH (-30.0f)

// ---------------------------------------------------------------------------
// Kernel 1: per (b, chunk) compute per-h sums of A over the 64 chunk steps.
// A layout: A[b, t, h] -> flat (b*T + t)*H + h. For one (b,chunk) the region
// [chunk*64 .. chunk*64+64) x H is 1024 contiguous floats -> coalesced float4.
// cs layout: cs[(b*H + h)*C + c]
__global__ void __launch_bounds__(256) k_chunk_sums(const float* __restrict__ A,
                                                    float* __restrict__ cs) {
    int blk = blockIdx.x;
    int b = blk / C_SZ;
    int c = blk % C_SZ;
    __shared__ float a_sh[L_SZ * H_SZ];  // 1024 floats
    const float4* src =
        (const float4*)(A + ((size_t)b * T_SZ + (size_t)c * L_SZ) * H_SZ);
    int tid = threadIdx.x;
    ((float4*)a_sh)[tid] = src[tid];
    __syncthreads();
    if (tid < H_SZ) {
        float s = 0.f;
        #pragma unroll 8
        for (int i = 0; i < L_SZ; ++i) s += a_sh[i * H_SZ + tid];
        cs[((size_t)b * H_SZ + tid) * C_SZ + c] = s;
    }
}

// ---------------------------------------------------------------------------
// Kernel 2: per (b,h) strict suffix sums over the 128 chunk sums.
// saf[bh*C + k] = sum_{j>k} cs[bh*C + j]
__global__ void k_suffix(const float* __restrict__ cs, float* __restrict__ saf) {
    int bh = blockIdx.x;
    if (threadIdx.x == 0) {
        float acc = 0.f;
        for (int k = C_SZ - 1; k >= 0; --k) {
            saf[(size_t)bh * C_SZ + k] = acc;
            acc += cs[(size_t)bh * C_SZ + k];
        }
    }
}

// ---------------------------------------------------------------------------
// Kernel 3: main. One block per (b,h,c). Early-exit on negligible weight.
// Active blocks: stage w[t]*X[t,:] and B[t,:] chunk panels (64x64 each) into
// LDS, compute C[p,n] = sum_t xw[t,p]*B[t,n] with 4x4 register tiles,
// atomicAdd into out[b,h,p,n].
__global__ void __launch_bounds__(256) k_states(const float* __restrict__ X,
                                                const float* __restrict__ A,
                                                const float* __restrict__ Bm,
                                                const float* __restrict__ saf,
                                                float* __restrict__ out) {
    const int c = blockIdx.x;
    const int h = blockIdx.y;
    const int b = blockIdx.z;

    const float safter = saf[((size_t)b * H_SZ + h) * C_SZ + c];
    if (safter < SKIP_THRESH) return;  // uniform across block

    __shared__ float a_sh[L_SZ];
    __shared__ float w_sh[L_SZ];
    __shared__ float xw_sh[L_SZ * P_SZ];  // 16 KB
    __shared__ float b_sh[L_SZ * N_SZ];   // 16 KB

    const int tid = threadIdx.x;
    const size_t base_t = (size_t)b * T_SZ + (size_t)c * L_SZ;

    // ---- issue global loads for X and B chunk panels into registers ----
    // Row i of the X panel: X[(base_t+i)*H*P + h*P + 0..63]; rows stride H*P.
    const float* Xp = X + (base_t * H_SZ + h) * (size_t)P_SZ;
    const float* Bp = Bm + (base_t * H_SZ + h) * (size_t)N_SZ;
    float4 xr[4], br[4];
    #pragma unroll
    for (int k = 0; k < 4; ++k) {
        int idx = tid + k * 256;       // 0..1023 float4 index
        int row = idx >> 4;            // 0..63
        int col = idx & 15;            // float4 column
        xr[k] = *(const float4*)(Xp + (size_t)row * (H_SZ * P_SZ) + col * 4);
        br[k] = *(const float4*)(Bp + (size_t)row * (H_SZ * N_SZ) + col * 4);
    }

    // ---- chunk-local A and strict suffix sums -> weights ----
    if (tid < L_SZ) a_sh[tid] = A[(base_t + tid) * H_SZ + h];
    __syncthreads();
    if (tid == 0) {
        float acc = 0.f;
        for (int i = L_SZ - 1; i >= 0; --i) {
            w_sh[i] = acc;       // strict suffix within chunk
            acc += a_sh[i];
        }
    }
    __syncthreads();
    if (tid < L_SZ) w_sh[tid] = expf(w_sh[tid] + safter);
    __syncthreads();

    // ---- scale X rows by w[row], stage both panels to LDS ----
    #pragma unroll
    for (int k = 0; k < 4; ++k) {
        int idx = tid + k * 256;
        int row = idx >> 4;
        float wv = w_sh[row];
        float4 xv = xr[k];
        xv.x *= wv; xv.y *= wv; xv.z *= wv; xv.w *= wv;
        ((float4*)xw_sh)[idx] = xv;
        ((float4*)b_sh)[idx] = br[k];
    }
    __syncthreads();

    // ---- 64x64 output tile, 4x4 per thread, K=64 ----
    const int pi = (tid >> 4) << 2;  // 0,4,...,60
    const int ni = (tid & 15) << 2;
    float acc00 = 0.f, acc01 = 0.f, acc02 = 0.f, acc03 = 0.f;
    float acc10 = 0.f, acc11 = 0.f, acc12 = 0.f, acc13 = 0.f;
    float acc20 = 0.f, acc21 = 0.f, acc22 = 0.f, acc23 = 0.f;
    float acc30 = 0.f, acc31 = 0.f, acc32 = 0.f, acc33 = 0.f;
    #pragma unroll 4
    for (int t = 0; t < L_SZ; ++t) {
        float4 xv = *(const float4*)(xw_sh + t * P_SZ + pi);
        float4 bv = *(const float4*)(b_sh + t * N_SZ + ni);
        acc00 += xv.x * bv.x; acc01 += xv.x * bv.y; acc02 += xv.x * bv.z; acc03 += xv.x * bv.w;
        acc10 += xv.y * bv.x; acc11 += xv.y * bv.y; acc12 += xv.y * bv.z; acc13 += xv.y * bv.w;
        acc20 += xv.z * bv.x; acc21 += xv.z * bv.y; acc22 += xv.z * bv.z; acc23 += xv.z * bv.w;
        acc30 += xv.w * bv.x; acc31 += xv.w * bv.y; acc32 += xv.w * bv.z; acc33 += xv.w * bv.w;
    }

    // ---- accumulate into output (low contention: ~active-chunks per addr) ----
    float* op = out + (((size_t)b * H_SZ + h) * P_SZ) * N_SZ;
    atomicAdd(op + (pi + 0) * N_SZ + ni + 0, acc00);
    atomicAdd(op + (pi + 0) * N_SZ + ni + 1, acc01);
    atomicAdd(op + (pi + 0) * N_SZ + ni + 2, acc02);
    atomicAdd(op + (pi + 0) * N_SZ + ni + 3, acc03);
    atomicAdd(op + (pi + 1) * N_SZ + ni + 0, acc10);
    atomicAdd(op + (pi + 1) * N_SZ + ni + 1, acc11);
    atomicAdd(op + (pi + 1) * N_SZ + ni + 2, acc12);
    atomicAdd(op + (pi + 1) * N_SZ + ni + 3, acc13);
    atomicAdd(op + (pi + 2) * N_SZ + ni + 0, acc20);
    atomicAdd(op + (pi + 2) * N_SZ + ni + 1, acc21);
    atomicAdd(op + (pi + 2) * N_SZ + ni + 2, acc22);
    atomicAdd(op + (pi + 2) * N_SZ + ni + 3, acc23);
    atomicAdd(op + (pi + 3) * N_SZ + ni + 0, acc30);
    atomicAdd(op + (pi + 3) * N_SZ + ni + 1, acc31);
    atomicAdd(op + (pi + 3) * N_SZ + ni + 2, acc32);
    atomicAdd(op + (pi + 3) * N_SZ + ni + 3, acc33);
}

extern "C" void kernel_launch(void* const* d_in, const int* in_sizes, int n_in,
                              void* d_out, int out_size, void* d_ws, size_t ws_size,
                              hipStream_t stream) {
    const float* X  = (const float*)d_in[0];  // [b,T,h,p]
    const float* A  = (const float*)d_in[1];  // [b,T,h]
    const float* Bm = (const float*)d_in[2];  // [b,T,h,n]
    float* out = (float*)d_out;               // [b,h,p,n] fp32

    float* cs  = (float*)d_ws;                     // [b*h, C] chunk sums
    float* saf = cs + (size_t)B_SZ * H_SZ * C_SZ;  // [b*h, C] suffix-after sums

    // d_out is poisoned each call; atomics need zeros.
    hipMemsetAsync(d_out, 0, (size_t)out_size * sizeof(float), stream);

    k_chunk_sums<<<B_SZ * C_SZ, 256, 0, stream>>>(A, cs);
    k_suffix<<<B_SZ * H_SZ, 64, 0, stream>>>(cs, saf);

    dim3 grid(C_SZ, H_SZ, B_SZ);
    k_states<<<grid, 256, 0, stream>>>(X, A, Bm, saf, out);
}

// Round 2
// 143.471 us; speedup vs baseline: 1.0190x; 1.0190x over previous
//
#include <hip/hip_runtime.h>

// Problem shape (fixed by setup_inputs): b=2, T=8192, h=16, p=64, n=64, l=64
#define B_SZ 2
#define T_SZ 8192
#define H_SZ 16
#define P_SZ 64
#define N_SZ 64
#define L_SZ 64
#define C_SZ (T_SZ / L_SZ)   // 128 chunks
// Skip threshold on the after-chunk suffix sum. exp(-30) ~ 9e-14; worst-case
// skipped contribution ~1e-8 vs validation threshold ~0.3. Very conservative.
#define SKIP_THRESH (-30.0f)

// ---------------------------------------------------------------------------
// Kernel 1: per (b, chunk) compute per-h sums of A over the 64 chunk steps,
// AND zero this block's 512-float slice of out (fused memset — kernel
// boundary orders it before k_main's atomics).
// A layout: A[b, t, h] -> flat (b*T + t)*H + h. For one (b,chunk) the region
// is 1024 contiguous floats -> coalesced float4.
// cs layout: cs[(b*H + h)*C + c]
__global__ void __launch_bounds__(256) k_prep(const float* __restrict__ A,
                                              float* __restrict__ cs,
                                              float* __restrict__ out) {
    const int blk = blockIdx.x;       // 0..255 == B_SZ*C_SZ-1
    const int b = blk / C_SZ;
    const int c = blk % C_SZ;
    const int tid = threadIdx.x;
    __shared__ float a_sh[L_SZ * H_SZ];  // 1024 floats
    const float4* src =
        (const float4*)(A + ((size_t)b * T_SZ + (size_t)c * L_SZ) * H_SZ);
    ((float4*)a_sh)[tid] = src[tid];

    // zero out: 131072 floats / 256 blocks = 512 floats = 128 float4 per block
    if (tid < 128) {
        float4 z; z.x = z.y = z.z = z.w = 0.f;
        ((float4*)out)[(size_t)blk * 128 + tid] = z;
    }
    __syncthreads();
    if (tid < H_SZ) {
        float s = 0.f;
        #pragma unroll
        for (int i = 0; i < L_SZ; ++i) s += a_sh[i * H_SZ + tid];
        cs[((size_t)b * H_SZ + tid) * C_SZ + c] = s;
    }
}

// ---------------------------------------------------------------------------
// Kernel 2: main. One block per (b,h,c). Computes its own after-chunk suffix
// sum by parallel reduction over cs (L2-resident, 16 KB), early-exits on
// negligible weight, else stages w[t]*X and B panels to LDS, computes the
// 64x64 fp32 tile (4x4 per thread), atomicAdds into out.
__global__ void __launch_bounds__(256) k_main(const float* __restrict__ X,
                                              const float* __restrict__ A,
                                              const float* __restrict__ Bm,
                                              const float* __restrict__ cs,
                                              float* __restrict__ out) {
    const int c = blockIdx.x;
    const int h = blockIdx.y;
    const int b = blockIdx.z;
    const int bh = b * H_SZ + h;
    const int tid = threadIdx.x;

    __shared__ float red[128];
    __shared__ float s_saf;
    __shared__ float w_sh[L_SZ];
    __shared__ float xw_sh[L_SZ * P_SZ];  // 16 KB
    __shared__ float b_sh[L_SZ * N_SZ];   // 16 KB

    // ---- suffix-after sum over later chunks: tree reduce of <=127 values ----
    if (tid < 128)
        red[tid] = (tid > c) ? cs[(size_t)bh * C_SZ + tid] : 0.f;
    __syncthreads();
    if (tid < 64) {
        float x = red[tid] + red[tid + 64];
        x += __shfl_down(x, 32);
        x += __shfl_down(x, 16);
        x += __shfl_down(x, 8);
        x += __shfl_down(x, 4);
        x += __shfl_down(x, 2);
        x += __shfl_down(x, 1);
        if (tid == 0) s_saf = x;
    }
    __syncthreads();
    const float safter = s_saf;
    if (safter < SKIP_THRESH) return;  // uniform across block

    const size_t base_t = (size_t)b * T_SZ + (size_t)c * L_SZ;

    // ---- issue global loads for X and B chunk panels into registers ----
    const float* Xp = X + (base_t * H_SZ + h) * (size_t)P_SZ;
    const float* Bp = Bm + (base_t * H_SZ + h) * (size_t)N_SZ;
    float4 xr[4], br[4];
    #pragma unroll
    for (int k = 0; k < 4; ++k) {
        int idx = tid + k * 256;       // 0..1023 float4 index
        int row = idx >> 4;            // 0..63
        int col = idx & 15;            // float4 column
        xr[k] = *(const float4*)(Xp + (size_t)row * (H_SZ * P_SZ) + col * 4);
        br[k] = *(const float4*)(Bp + (size_t)row * (H_SZ * N_SZ) + col * 4);
    }

    // ---- intra-chunk weights via wave-0 shuffle scan (6 steps) ----
    if (tid < 64) {
        float incl = A[(base_t + tid) * H_SZ + h];
        #pragma unroll
        for (int off = 1; off < 64; off <<= 1) {
            float y = __shfl_up(incl, off);
            if (tid >= off) incl += y;
        }
        float total = __shfl(incl, 63);
        // strict suffix within chunk = total - inclusive; plus inter-chunk term
        w_sh[tid] = __expf(total - incl + safter);
    }
    __syncthreads();

    // ---- scale X rows by w[row], stage both panels to LDS ----
    #pragma unroll
    for (int k = 0; k < 4; ++k) {
        int idx = tid + k * 256;
        int row = idx >> 4;
        float wv = w_sh[row];
        float4 xv = xr[k];
        xv.x *= wv; xv.y *= wv; xv.z *= wv; xv.w *= wv;
        ((float4*)xw_sh)[idx] = xv;
        ((float4*)b_sh)[idx] = br[k];
    }
    __syncthreads();

    // ---- 64x64 output tile, 4x4 per thread, K=64 ----
    const int pi = (tid >> 4) << 2;  // 0,4,...,60
    const int ni = (tid & 15) << 2;
    float acc00 = 0.f, acc01 = 0.f, acc02 = 0.f, acc03 = 0.f;
    float acc10 = 0.f, acc11 = 0.f, acc12 = 0.f, acc13 = 0.f;
    float acc20 = 0.f, acc21 = 0.f, acc22 = 0.f, acc23 = 0.f;
    float acc30 = 0.f, acc31 = 0.f, acc32 = 0.f, acc33 = 0.f;
    #pragma unroll 4
    for (int t = 0; t < L_SZ; ++t) {
        float4 xv = *(const float4*)(xw_sh + t * P_SZ + pi);
        float4 bv = *(const float4*)(b_sh + t * N_SZ + ni);
        acc00 += xv.x * bv.x; acc01 += xv.x * bv.y; acc02 += xv.x * bv.z; acc03 += xv.x * bv.w;
        acc10 += xv.y * bv.x; acc11 += xv.y * bv.y; acc12 += xv.y * bv.z; acc13 += xv.y * bv.w;
        acc20 += xv.z * bv.x; acc21 += xv.z * bv.y; acc22 += xv.z * bv.z; acc23 += xv.z * bv.w;
        acc30 += xv.w * bv.x; acc31 += xv.w * bv.y; acc32 += xv.w * bv.z; acc33 += xv.w * bv.w;
    }

    // ---- accumulate into output (~7 active chunks per address) ----
    float* op = out + (((size_t)b * H_SZ + h) * P_SZ) * N_SZ;
    atomicAdd(op + (pi + 0) * N_SZ + ni + 0, acc00);
    atomicAdd(op + (pi + 0) * N_SZ + ni + 1, acc01);
    atomicAdd(op + (pi + 0) * N_SZ + ni + 2, acc02);
    atomicAdd(op + (pi + 0) * N_SZ + ni + 3, acc03);
    atomicAdd(op + (pi + 1) * N_SZ + ni + 0, acc10);
    atomicAdd(op + (pi + 1) * N_SZ + ni + 1, acc11);
    atomicAdd(op + (pi + 1) * N_SZ + ni + 2, acc12);
    atomicAdd(op + (pi + 1) * N_SZ + ni + 3, acc13);
    atomicAdd(op + (pi + 2) * N_SZ + ni + 0, acc20);
    atomicAdd(op + (pi + 2) * N_SZ + ni + 1, acc21);
    atomicAdd(op + (pi + 2) * N_SZ + ni + 2, acc22);
    atomicAdd(op + (pi + 2) * N_SZ + ni + 3, acc23);
    atomicAdd(op + (pi + 3) * N_SZ + ni + 0, acc30);
    atomicAdd(op + (pi + 3) * N_SZ + ni + 1, acc31);
    atomicAdd(op + (pi + 3) * N_SZ + ni + 2, acc32);
    atomicAdd(op + (pi + 3) * N_SZ + ni + 3, acc33);
}

extern "C" void kernel_launch(void* const* d_in, const int* in_sizes, int n_in,
                              void* d_out, int out_size, void* d_ws, size_t ws_size,
                              hipStream_t stream) {
    const float* X  = (const float*)d_in[0];  // [b,T,h,p]
    const float* A  = (const float*)d_in[1];  // [b,T,h]
    const float* Bm = (const float*)d_in[2];  // [b,T,h,n]
    float* out = (float*)d_out;               // [b,h,p,n] fp32

    float* cs = (float*)d_ws;                 // [b*h, C] chunk sums

    k_prep<<<B_SZ * C_SZ, 256, 0, stream>>>(A, cs, out);

    dim3 grid(C_SZ, H_SZ, B_SZ);
    k_main<<<grid, 256, 0, stream>>>(X, A, Bm, cs, out);
}

// Round 3
// 139.323 us; speedup vs baseline: 1.0494x; 1.0298x over previous
//
#include <hip/hip_runtime.h>

// Problem shape (fixed by setup_inputs): b=2, T=8192, h=16, p=64, n=64, l=64
#define B_SZ 2
#define T_SZ 8192
#define H_SZ 16
#define P_SZ 64
#define N_SZ 64
#define L_SZ 64
#define C_SZ (T_SZ / L_SZ)   // 128 chunks
#define CGROUPS 16           // k_main: chunks-per-block stride
// Skip threshold on the after-chunk suffix sum. exp(-30) ~ 9e-14; worst-case
// skipped contribution ~1e-8 vs validation threshold ~0.3. Very conservative.
#define SKIP_THRESH (-30.0f)

// ---------------------------------------------------------------------------
// Kernel 1: per (b, chunk) compute per-h sums of A over the 64 chunk steps,
// AND zero this block's 512-float slice of out (fused memset — kernel
// boundary orders it before k_main's atomics).
// A layout: A[b, t, h] -> flat (b*T + t)*H + h. cs layout: cs[(b*H+h)*C + c]
__global__ void __launch_bounds__(256) k_prep(const float* __restrict__ A,
                                              float* __restrict__ cs,
                                              float* __restrict__ out) {
    const int blk = blockIdx.x;       // 0..255 == B_SZ*C_SZ-1
    const int b = blk / C_SZ;
    const int c = blk % C_SZ;
    const int tid = threadIdx.x;
    __shared__ float a_sh[L_SZ * H_SZ];  // 1024 floats
    const float4* src =
        (const float4*)(A + ((size_t)b * T_SZ + (size_t)c * L_SZ) * H_SZ);
    ((float4*)a_sh)[tid] = src[tid];

    // zero out: 131072 floats / 256 blocks = 512 floats = 128 float4 per block
    if (tid < 128) {
        float4 z; z.x = z.y = z.z = z.w = 0.f;
        ((float4*)out)[(size_t)blk * 128 + tid] = z;
    }
    __syncthreads();
    if (tid < H_SZ) {
        float s = 0.f;
        #pragma unroll
        for (int i = 0; i < L_SZ; ++i) s += a_sh[i * H_SZ + tid];
        cs[((size_t)b * H_SZ + tid) * C_SZ + c] = s;
    }
}

// ---------------------------------------------------------------------------
// Kernel 2: main. Grid (CGROUPS, H, B) = 512 blocks. Each block computes the
// full 128-entry suffix scan of cs once (two-wave shuffle scan), then strides
// over chunks c = gx, gx+16, ..., doing panel work only where the weight is
// non-negligible (~7 active chunks per (b,h), landing on distinct gx).
__global__ void __launch_bounds__(256) k_main(const float* __restrict__ X,
                                              const float* __restrict__ A,
                                              const float* __restrict__ Bm,
                                              const float* __restrict__ cs,
                                              float* __restrict__ out) {
    const int gx = blockIdx.x;
    const int h = blockIdx.y;
    const int b = blockIdx.z;
    const int bh = b * H_SZ + h;
    const int tid = threadIdx.x;

    __shared__ float saf_sh[C_SZ];   // strict suffix-after per chunk
    __shared__ float wtot[2];
    __shared__ float w_sh[L_SZ];
    __shared__ float xw_sh[L_SZ * P_SZ];  // 16 KB
    __shared__ float b_sh[L_SZ * N_SZ];   // 16 KB

    // ---- full suffix scan over 128 chunk sums (waves 0 and 1) ----
    if (tid < 128) {
        const int lane = tid & 63;
        const int wv = tid >> 6;
        float incl = cs[(size_t)bh * C_SZ + tid];
        #pragma unroll
        for (int off = 1; off < 64; off <<= 1) {
            float y = __shfl_up(incl, off);
            if (lane >= off) incl += y;
        }
        if (lane == 63) wtot[wv] = incl;
        __builtin_amdgcn_s_waitcnt(0);  // no-op safety; real sync below
    }
    __syncthreads();
    if (tid < 128) {
        const int wv = tid >> 6;
        float incl_full = saf_sh[0];  // placeholder avoid unused warn (overwritten)
        (void)incl_full;
    }
    // second pass: apply cross-wave offset and write suffix values
    if (tid < 128) {
        const int lane = tid & 63;
        const int wv = tid >> 6;
        // recompute scan (registers from the block above are gone across the
        // barrier only if we split scopes — keep it simple: redo the scan)
        float incl = cs[(size_t)bh * C_SZ + tid];
        #pragma unroll
        for (int off = 1; off < 64; off <<= 1) {
            float y = __shfl_up(incl, off);
            if (lane >= off) incl += y;
        }
        float total = wtot[0] + wtot[1];
        if (wv == 1) incl += wtot[0];
        saf_sh[tid] = total - incl;   // strict suffix after chunk tid
    }
    __syncthreads();

    const int pi = (tid >> 4) << 2;  // 0,4,...,60
    const int ni = (tid & 15) << 2;
    float* op = out + (((size_t)b * H_SZ + h) * P_SZ) * N_SZ;

    for (int c = gx; c < C_SZ; c += CGROUPS) {
        const float safter = saf_sh[c];     // uniform across block
        if (safter < SKIP_THRESH) continue;

        const size_t base_t = (size_t)b * T_SZ + (size_t)c * L_SZ;
        const float* Xp = X + (base_t * H_SZ + h) * (size_t)P_SZ;
        const float* Bp = Bm + (base_t * H_SZ + h) * (size_t)N_SZ;

        // ---- issue global loads for X and B chunk panels into registers ----
        float4 xr[4], br[4];
        #pragma unroll
        for (int k = 0; k < 4; ++k) {
            int idx = tid + k * 256;       // 0..1023 float4 index
            int row = idx >> 4;            // 0..63
            int col = idx & 15;            // float4 column
            xr[k] = *(const float4*)(Xp + (size_t)row * (H_SZ * P_SZ) + col * 4);
            br[k] = *(const float4*)(Bp + (size_t)row * (H_SZ * N_SZ) + col * 4);
        }

        // ---- intra-chunk weights via wave-0 shuffle scan ----
        if (tid < 64) {
            float incl = A[(base_t + tid) * H_SZ + h];
            #pragma unroll
            for (int off = 1; off < 64; off <<= 1) {
                float y = __shfl_up(incl, off);
                if (tid >= off) incl += y;
            }
            float total = __shfl(incl, 63);
            w_sh[tid] = __expf(total - incl + safter);
        }
        __syncthreads();

        // ---- scale X rows by w[row], stage both panels to LDS ----
        #pragma unroll
        for (int k = 0; k < 4; ++k) {
            int idx = tid + k * 256;
            int row = idx >> 4;
            float wv = w_sh[row];
            float4 xv = xr[k];
            xv.x *= wv; xv.y *= wv; xv.z *= wv; xv.w *= wv;
            ((float4*)xw_sh)[idx] = xv;
            ((float4*)b_sh)[idx] = br[k];
        }
        __syncthreads();

        // ---- 64x64 output tile, 4x4 per thread, K=64 ----
        float acc00 = 0.f, acc01 = 0.f, acc02 = 0.f, acc03 = 0.f;
        float acc10 = 0.f, acc11 = 0.f, acc12 = 0.f, acc13 = 0.f;
        float acc20 = 0.f, acc21 = 0.f, acc22 = 0.f, acc23 = 0.f;
        float acc30 = 0.f, acc31 = 0.f, acc32 = 0.f, acc33 = 0.f;
        #pragma unroll 4
        for (int t = 0; t < L_SZ; ++t) {
            float4 xv = *(const float4*)(xw_sh + t * P_SZ + pi);
            float4 bv = *(const float4*)(b_sh + t * N_SZ + ni);
            acc00 += xv.x * bv.x; acc01 += xv.x * bv.y; acc02 += xv.x * bv.z; acc03 += xv.x * bv.w;
            acc10 += xv.y * bv.x; acc11 += xv.y * bv.y; acc12 += xv.y * bv.z; acc13 += xv.y * bv.w;
            acc20 += xv.z * bv.x; acc21 += xv.z * bv.y; acc22 += xv.z * bv.z; acc23 += xv.z * bv.w;
            acc30 += xv.w * bv.x; acc31 += xv.w * bv.y; acc32 += xv.w * bv.z; acc33 += xv.w * bv.w;
        }

        // ---- accumulate into output (~7 active chunks per address) ----
        atomicAdd(op + (pi + 0) * N_SZ + ni + 0, acc00);
        atomicAdd(op + (pi + 0) * N_SZ + ni + 1, acc01);
        atomicAdd(op + (pi + 0) * N_SZ + ni + 2, acc02);
        atomicAdd(op + (pi + 0) * N_SZ + ni + 3, acc03);
        atomicAdd(op + (pi + 1) * N_SZ + ni + 0, acc10);
        atomicAdd(op + (pi + 1) * N_SZ + ni + 1, acc11);
        atomicAdd(op + (pi + 1) * N_SZ + ni + 2, acc12);
        atomicAdd(op + (pi + 1) * N_SZ + ni + 3, acc13);
        atomicAdd(op + (pi + 2) * N_SZ + ni + 0, acc20);
        atomicAdd(op + (pi + 2) * N_SZ + ni + 1, acc21);
        atomicAdd(op + (pi + 2) * N_SZ + ni + 2, acc22);
        atomicAdd(op + (pi + 2) * N_SZ + ni + 3, acc23);
        atomicAdd(op + (pi + 3) * N_SZ + ni + 0, acc30);
        atomicAdd(op + (pi + 3) * N_SZ + ni + 1, acc31);
        atomicAdd(op + (pi + 3) * N_SZ + ni + 2, acc32);
        atomicAdd(op + (pi + 3) * N_SZ + ni + 3, acc33);

        __syncthreads();  // protect LDS before next active iteration
    }
}

extern "C" void kernel_launch(void* const* d_in, const int* in_sizes, int n_in,
                              void* d_out, int out_size, void* d_ws, size_t ws_size,
                              hipStream_t stream) {
    const float* X  = (const float*)d_in[0];  // [b,T,h,p]
    const float* A  = (const float*)d_in[1];  // [b,T,h]
    const float* Bm = (const float*)d_in[2];  // [b,T,h,n]
    float* out = (float*)d_out;               // [b,h,p,n] fp32

    float* cs = (float*)d_ws;                 // [b*h, C] chunk sums

    k_prep<<<B_SZ * C_SZ, 256, 0, stream>>>(A, cs, out);

    dim3 grid(CGROUPS, H_SZ, B_SZ);
    k_main<<<grid, 256, 0, stream>>>(X, A, Bm, cs, out);
}